// Round 9
// baseline (338.185 us; speedup 1.0000x reference)
//
#include <hip/hip_runtime.h>
#include <hip/hip_bf16.h>

#define T_TOK 2048
#define DDIM  1024
#define IDIM  1024
#define NEXP  8
#define TOPK  2
#define MAXROWS (T_TOK * TOPK)

#define BM 128
#define BN 64
#define BK 32

typedef __attribute__((ext_vector_type(8))) short          s16x8;
typedef __attribute__((ext_vector_type(8))) unsigned short u16x8;
typedef __attribute__((ext_vector_type(4))) float          f32x4;

__device__ __forceinline__ unsigned short f2bf(float f) {
    return __builtin_bit_cast(unsigned short, __float2bfloat16(f));
}

__device__ __forceinline__ u16x8 pack8(const float4& a, const float4& b) {
    u16x8 v;
    v[0] = f2bf(a.x); v[1] = f2bf(a.y); v[2] = f2bf(a.z); v[3] = f2bf(a.w);
    v[4] = f2bf(b.x); v[5] = f2bf(b.y); v[6] = f2bf(b.z); v[7] = f2bf(b.w);
    return v;
}

__device__ __forceinline__ s16x8 cvt8(const float4& a, const float4& b) {
    return __builtin_bit_cast(s16x8, pack8(a, b));
}

// ---------------- routing: build per-expert compact token lists ----------------
__global__ void route_kernel(const int* __restrict__ indices,
                             const float* __restrict__ weights,
                             const void* __restrict__ mask,
                             int* __restrict__ counts, int* __restrict__ offsets,
                             int* __restrict__ tok, float* __restrict__ wslot) {
    __shared__ int cnt[NEXP], offs[NEXP], cur[NEXP];
    __shared__ int is_u8;
    const int tid = threadIdx.x;
    const unsigned char* m8  = (const unsigned char*)mask;
    const int*           m32 = (const int*)mask;
    if (tid < NEXP) cnt[tid] = 0;
    if (tid == 0) is_u8 = 0;
    __syncthreads();
    int found = 0;
    for (int i = tid; i < T_TOK; i += blockDim.x)
        if ((i & 3) != 0 && m8[i] != 0) found = 1;
    if (found) atomicOr(&is_u8, 1);
    __syncthreads();
    const int u8mode = is_u8;
    for (int idx = tid; idx < MAXROWS; idx += blockDim.x) {
        int t = idx >> 1;  // K = 2
        int active = u8mode ? (m8[t] != 0) : (m32[t] != 0);
        if (active) atomicAdd(&cnt[indices[idx]], 1);
    }
    __syncthreads();
    if (tid == 0) {
        int run = 0;
        for (int e = 0; e < NEXP; ++e) { offs[e] = run; run += cnt[e]; }
    }
    __syncthreads();
    if (tid < NEXP) { counts[tid] = cnt[tid]; offsets[tid] = offs[tid]; cur[tid] = offs[tid]; }
    __syncthreads();
    for (int idx = tid; idx < MAXROWS; idx += blockDim.x) {
        int t = idx >> 1;
        int active = u8mode ? (m8[t] != 0) : (m32[t] != 0);
        if (active) {
            int e = indices[idx];
            int p = atomicAdd(&cur[e], 1);
            tok[p]   = t;
            wslot[p] = weights[idx];
        }
    }
}

// ---------------- x: f32 -> bf16 once ----------------
__global__ __launch_bounds__(256) void cvt_x_kernel(const float* __restrict__ x,
                                                    unsigned short* __restrict__ xb) {
    int i = (blockIdx.x * 256 + threadIdx.x) * 8;
    float4 a = *reinterpret_cast<const float4*>(x + i);
    float4 b = *reinterpret_cast<const float4*>(x + i + 4);
    *reinterpret_cast<u16x8*>(xb + i) = pack8(a, b);
}

// ---------------- GEMM1: H = silu(X G^T) * (X U^T) — register-direct, no LDS ----------------
// 256 threads = 4 waves (2 wm x 2 wn); wave tile = 64 rows x 32 cols.
// A fragments gathered from xb (bf16) per lane; B fragments loaded f32 from
// gate/up rows (K-contiguous) and converted in-register. No barriers.
__global__ __launch_bounds__(256, 3) void gemm1_kernel(
    const unsigned short* __restrict__ xb,
    const float* __restrict__ gate, const float* __restrict__ up,
    const int* __restrict__ counts, const int* __restrict__ offsets,
    const int* __restrict__ tok, unsigned short* __restrict__ hb) {
    const int e     = blockIdx.z;
    const int n_e   = counts[e];
    const int tileM = blockIdx.y;
    if (tileM * BM >= n_e) return;
    const int off = offsets[e];
    const int n0  = blockIdx.x * BN;

    const int tid  = threadIdx.x;
    const int lane = tid & 63;
    const int wid  = tid >> 6;
    const int wm   = wid >> 1, wn = wid & 1;
    const int fr   = lane & 15;
    const int s8   = lane >> 4;

    // per-lane A row pointers (token gather), m = 0..3
    const unsigned short* aP0;
    const unsigned short* aP1;
    const unsigned short* aP2;
    const unsigned short* aP3;
    {
        int r0 = tileM * BM + wm * 64 + 0 * 16 + fr;
        int r1 = tileM * BM + wm * 64 + 1 * 16 + fr;
        int r2 = tileM * BM + wm * 64 + 2 * 16 + fr;
        int r3 = tileM * BM + wm * 64 + 3 * 16 + fr;
        int t0 = (r0 < n_e) ? tok[off + r0] : tok[off];
        int t1 = (r1 < n_e) ? tok[off + r1] : tok[off];
        int t2 = (r2 < n_e) ? tok[off + r2] : tok[off];
        int t3 = (r3 < n_e) ? tok[off + r3] : tok[off];
        aP0 = xb + (size_t)t0 * DDIM + s8 * 8;
        aP1 = xb + (size_t)t1 * DDIM + s8 * 8;
        aP2 = xb + (size_t)t2 * DDIM + s8 * 8;
        aP3 = xb + (size_t)t3 * DDIM + s8 * 8;
    }
    // per-lane B row pointers, nf = 0..1
    const float* gP0 = gate + ((size_t)e * IDIM + n0 + wn * 32 + 0 * 16 + fr) * DDIM + s8 * 8;
    const float* gP1 = gate + ((size_t)e * IDIM + n0 + wn * 32 + 1 * 16 + fr) * DDIM + s8 * 8;
    const float* uP0 = up   + ((size_t)e * IDIM + n0 + wn * 32 + 0 * 16 + fr) * DDIM + s8 * 8;
    const float* uP1 = up   + ((size_t)e * IDIM + n0 + wn * 32 + 1 * 16 + fr) * DDIM + s8 * 8;

    f32x4 accg[4][2] = {};
    f32x4 accu[4][2] = {};

#pragma unroll 2
    for (int k0 = 0; k0 < DDIM; k0 += BK) {
        s16x8 a0 = *reinterpret_cast<const s16x8*>(aP0 + k0);
        s16x8 a1 = *reinterpret_cast<const s16x8*>(aP1 + k0);
        s16x8 a2 = *reinterpret_cast<const s16x8*>(aP2 + k0);
        s16x8 a3 = *reinterpret_cast<const s16x8*>(aP3 + k0);
        float4 g00 = *reinterpret_cast<const float4*>(gP0 + k0);
        float4 g01 = *reinterpret_cast<const float4*>(gP0 + k0 + 4);
        float4 g10 = *reinterpret_cast<const float4*>(gP1 + k0);
        float4 g11 = *reinterpret_cast<const float4*>(gP1 + k0 + 4);
        float4 u00 = *reinterpret_cast<const float4*>(uP0 + k0);
        float4 u01 = *reinterpret_cast<const float4*>(uP0 + k0 + 4);
        float4 u10 = *reinterpret_cast<const float4*>(uP1 + k0);
        float4 u11 = *reinterpret_cast<const float4*>(uP1 + k0 + 4);
        s16x8 bg0 = cvt8(g00, g01);
        s16x8 bg1 = cvt8(g10, g11);
        s16x8 bu0 = cvt8(u00, u01);
        s16x8 bu1 = cvt8(u10, u11);
        accg[0][0] = __builtin_amdgcn_mfma_f32_16x16x32_bf16(a0, bg0, accg[0][0], 0, 0, 0);
        accg[0][1] = __builtin_amdgcn_mfma_f32_16x16x32_bf16(a0, bg1, accg[0][1], 0, 0, 0);
        accg[1][0] = __builtin_amdgcn_mfma_f32_16x16x32_bf16(a1, bg0, accg[1][0], 0, 0, 0);
        accg[1][1] = __builtin_amdgcn_mfma_f32_16x16x32_bf16(a1, bg1, accg[1][1], 0, 0, 0);
        accg[2][0] = __builtin_amdgcn_mfma_f32_16x16x32_bf16(a2, bg0, accg[2][0], 0, 0, 0);
        accg[2][1] = __builtin_amdgcn_mfma_f32_16x16x32_bf16(a2, bg1, accg[2][1], 0, 0, 0);
        accg[3][0] = __builtin_amdgcn_mfma_f32_16x16x32_bf16(a3, bg0, accg[3][0], 0, 0, 0);
        accg[3][1] = __builtin_amdgcn_mfma_f32_16x16x32_bf16(a3, bg1, accg[3][1], 0, 0, 0);
        accu[0][0] = __builtin_amdgcn_mfma_f32_16x16x32_bf16(a0, bu0, accu[0][0], 0, 0, 0);
        accu[0][1] = __builtin_amdgcn_mfma_f32_16x16x32_bf16(a0, bu1, accu[0][1], 0, 0, 0);
        accu[1][0] = __builtin_amdgcn_mfma_f32_16x16x32_bf16(a1, bu0, accu[1][0], 0, 0, 0);
        accu[1][1] = __builtin_amdgcn_mfma_f32_16x16x32_bf16(a1, bu1, accu[1][1], 0, 0, 0);
        accu[2][0] = __builtin_amdgcn_mfma_f32_16x16x32_bf16(a2, bu0, accu[2][0], 0, 0, 0);
        accu[2][1] = __builtin_amdgcn_mfma_f32_16x16x32_bf16(a2, bu1, accu[2][1], 0, 0, 0);
        accu[3][0] = __builtin_amdgcn_mfma_f32_16x16x32_bf16(a3, bu0, accu[3][0], 0, 0, 0);
        accu[3][1] = __builtin_amdgcn_mfma_f32_16x16x32_bf16(a3, bu1, accu[3][1], 0, 0, 0);
    }

    const int rbase = tileM * BM;
#pragma unroll
    for (int m = 0; m < 4; ++m)
#pragma unroll
        for (int n = 0; n < 2; ++n)
#pragma unroll
            for (int j = 0; j < 4; ++j) {
                int rl = wm * 64 + m * 16 + (lane >> 4) * 4 + j;
                if (rbase + rl < n_e) {
                    int col = wn * 32 + n * 16 + fr;
                    float g = accg[m][n][j];
                    float u = accu[m][n][j];
                    float h = (g / (1.0f + __expf(-g))) * u;
                    hb[(size_t)(off + rbase + rl) * IDIM + n0 + col] = f2bf(h);
                }
            }
}

// ---------------- GEMM2: Y_rows = H D^T, weighted scatter-add — register-direct ----------------
__global__ __launch_bounds__(256, 3) void gemm2_kernel(
    const unsigned short* __restrict__ hb, const float* __restrict__ down,
    const int* __restrict__ counts, const int* __restrict__ offsets,
    const int* __restrict__ tok, const float* __restrict__ wslot,
    float* __restrict__ y) {
    const int e     = blockIdx.z;
    const int n_e   = counts[e];
    const int tileM = blockIdx.y;
    if (tileM * BM >= n_e) return;
    const int off = offsets[e];
    const int n0  = blockIdx.x * BN;

    const int tid  = threadIdx.x;
    const int lane = tid & 63;
    const int wid  = tid >> 6;
    const int wm   = wid >> 1, wn = wid & 1;
    const int fr   = lane & 15;
    const int s8   = lane >> 4;

    const unsigned short* aP0;
    const unsigned short* aP1;
    const unsigned short* aP2;
    const unsigned short* aP3;
    {
        int r0 = tileM * BM + wm * 64 + 0 * 16 + fr;
        int r1 = tileM * BM + wm * 64 + 1 * 16 + fr;
        int r2 = tileM * BM + wm * 64 + 2 * 16 + fr;
        int r3 = tileM * BM + wm * 64 + 3 * 16 + fr;
        int h0 = (r0 < n_e) ? (off + r0) : off;
        int h1 = (r1 < n_e) ? (off + r1) : off;
        int h2 = (r2 < n_e) ? (off + r2) : off;
        int h3 = (r3 < n_e) ? (off + r3) : off;
        aP0 = hb + (size_t)h0 * IDIM + s8 * 8;
        aP1 = hb + (size_t)h1 * IDIM + s8 * 8;
        aP2 = hb + (size_t)h2 * IDIM + s8 * 8;
        aP3 = hb + (size_t)h3 * IDIM + s8 * 8;
    }
    const float* bP0 = down + ((size_t)e * DDIM + n0 + wn * 32 + 0 * 16 + fr) * IDIM + s8 * 8;
    const float* bP1 = down + ((size_t)e * DDIM + n0 + wn * 32 + 1 * 16 + fr) * IDIM + s8 * 8;

    f32x4 acc[4][2] = {};

#pragma unroll 2
    for (int k0 = 0; k0 < IDIM; k0 += BK) {
        s16x8 a0 = *reinterpret_cast<const s16x8*>(aP0 + k0);
        s16x8 a1 = *reinterpret_cast<const s16x8*>(aP1 + k0);
        s16x8 a2 = *reinterpret_cast<const s16x8*>(aP2 + k0);
        s16x8 a3 = *reinterpret_cast<const s16x8*>(aP3 + k0);
        float4 b00 = *reinterpret_cast<const float4*>(bP0 + k0);
        float4 b01 = *reinterpret_cast<const float4*>(bP0 + k0 + 4);
        float4 b10 = *reinterpret_cast<const float4*>(bP1 + k0);
        float4 b11 = *reinterpret_cast<const float4*>(bP1 + k0 + 4);
        s16x8 bf0 = cvt8(b00, b01);
        s16x8 bf1 = cvt8(b10, b11);
        acc[0][0] = __builtin_amdgcn_mfma_f32_16x16x32_bf16(a0, bf0, acc[0][0], 0, 0, 0);
        acc[0][1] = __builtin_amdgcn_mfma_f32_16x16x32_bf16(a0, bf1, acc[0][1], 0, 0, 0);
        acc[1][0] = __builtin_amdgcn_mfma_f32_16x16x32_bf16(a1, bf0, acc[1][0], 0, 0, 0);
        acc[1][1] = __builtin_amdgcn_mfma_f32_16x16x32_bf16(a1, bf1, acc[1][1], 0, 0, 0);
        acc[2][0] = __builtin_amdgcn_mfma_f32_16x16x32_bf16(a2, bf0, acc[2][0], 0, 0, 0);
        acc[2][1] = __builtin_amdgcn_mfma_f32_16x16x32_bf16(a2, bf1, acc[2][1], 0, 0, 0);
        acc[3][0] = __builtin_amdgcn_mfma_f32_16x16x32_bf16(a3, bf0, acc[3][0], 0, 0, 0);
        acc[3][1] = __builtin_amdgcn_mfma_f32_16x16x32_bf16(a3, bf1, acc[3][1], 0, 0, 0);
    }

    const int rbase = tileM * BM;
#pragma unroll
    for (int m = 0; m < 4; ++m)
#pragma unroll
        for (int n = 0; n < 2; ++n)
#pragma unroll
            for (int j = 0; j < 4; ++j) {
                int rl = wm * 64 + m * 16 + (lane >> 4) * 4 + j;
                if (rbase + rl < n_e) {
                    int col = wn * 32 + n * 16 + fr;
                    int row = off + rbase + rl;
                    float v = acc[m][n][j] * wslot[row];
                    atomicAdd(&y[(size_t)tok[row] * DDIM + n0 + col], v);
                }
            }
}

extern "C" void kernel_launch(void* const* d_in, const int* in_sizes, int n_in,
                              void* d_out, int out_size, void* d_ws, size_t ws_size,
                              hipStream_t stream) {
    const float* x       = (const float*)d_in[0];
    const void*  mask    = d_in[1];
    const float* weights = (const float*)d_in[2];
    const int*   indices = (const int*)d_in[3];
    const float* gate    = (const float*)d_in[4];
    const float* up      = (const float*)d_in[5];
    const float* down    = (const float*)d_in[6];
    float*       y       = (float*)d_out;

    char* ws = (char*)d_ws;
    int*            counts  = (int*)ws;
    int*            offsets = (int*)(ws + 32);
    int*            tok     = (int*)(ws + 256);
    float*          wslot   = (float*)(ws + 256 + MAXROWS * 4);
    unsigned short* xb      = (unsigned short*)(ws + 65536);
    unsigned short* hb      = (unsigned short*)(ws + 65536 + (size_t)T_TOK * DDIM * 2);

    hipMemsetAsync(d_out, 0, (size_t)out_size * sizeof(float), stream);
    route_kernel<<<1, 256, 0, stream>>>(indices, weights, mask, counts, offsets, tok, wslot);
    cvt_x_kernel<<<(T_TOK * DDIM / 8) / 256, 256, 0, stream>>>(x, xb);

    // y-tiles = 8 at BM=128 -> up to 1024 rows/expert (mean 512, sigma ~21)
    dim3 g1(IDIM / BN, 8, NEXP);
    gemm1_kernel<<<g1, 256, 0, stream>>>(xb, gate, up, counts, offsets, tok, hb);
    dim3 g2(DDIM / BN, 8, NEXP);
    gemm2_kernel<<<g2, 256, 0, stream>>>(hb, down, counts, offsets, tok, wslot, y);
}

// Round 10
// 146.997 us; speedup vs baseline: 2.3006x; 2.3006x over previous
//
#include <hip/hip_runtime.h>
#include <hip/hip_bf16.h>

#define T_TOK 2048
#define DDIM  1024
#define IDIM  1024
#define NEXP  8
#define TOPK  2
#define MAXROWS (T_TOK * TOPK)

#define BM 32
#define BN 64
#define BK 32
#define LDT 40                 // 80-B rows, 16B-aligned segs; read/write conflicts 2-way (free, m136)
#define ABUF (32 * LDT)
#define BBUF (64 * LDT)

typedef __attribute__((ext_vector_type(8))) short          s16x8;
typedef __attribute__((ext_vector_type(8))) unsigned short u16x8;
typedef __attribute__((ext_vector_type(4))) float          f32x4;

__device__ __forceinline__ unsigned short f2bf(float f) {
    return __builtin_bit_cast(unsigned short, __float2bfloat16(f));
}

__device__ __forceinline__ u16x8 pack8(const float4& a, const float4& b) {
    u16x8 v;
    v[0] = f2bf(a.x); v[1] = f2bf(a.y); v[2] = f2bf(a.z); v[3] = f2bf(a.w);
    v[4] = f2bf(b.x); v[5] = f2bf(b.y); v[6] = f2bf(b.z); v[7] = f2bf(b.w);
    return v;
}

// ---------------- routing: build per-expert compact token lists ----------------
__global__ void route_kernel(const int* __restrict__ indices,
                             const float* __restrict__ weights,
                             const void* __restrict__ mask,
                             int* __restrict__ counts, int* __restrict__ offsets,
                             int* __restrict__ tok, float* __restrict__ wslot) {
    __shared__ int cnt[NEXP], offs[NEXP], cur[NEXP];
    __shared__ int is_u8;
    const int tid = threadIdx.x;
    const unsigned char* m8  = (const unsigned char*)mask;
    const int*           m32 = (const int*)mask;
    if (tid < NEXP) cnt[tid] = 0;
    if (tid == 0) is_u8 = 0;
    __syncthreads();
    int found = 0;
    for (int i = tid; i < T_TOK; i += blockDim.x)
        if ((i & 3) != 0 && m8[i] != 0) found = 1;
    if (found) atomicOr(&is_u8, 1);
    __syncthreads();
    const int u8mode = is_u8;
    for (int idx = tid; idx < MAXROWS; idx += blockDim.x) {
        int t = idx >> 1;  // K = 2
        int active = u8mode ? (m8[t] != 0) : (m32[t] != 0);
        if (active) atomicAdd(&cnt[indices[idx]], 1);
    }
    __syncthreads();
    if (tid == 0) {
        int run = 0;
        for (int e = 0; e < NEXP; ++e) { offs[e] = run; run += cnt[e]; }
    }
    __syncthreads();
    if (tid < NEXP) { counts[tid] = cnt[tid]; offsets[tid] = offs[tid]; cur[tid] = offs[tid]; }
    __syncthreads();
    for (int idx = tid; idx < MAXROWS; idx += blockDim.x) {
        int t = idx >> 1;
        int active = u8mode ? (m8[t] != 0) : (m32[t] != 0);
        if (active) {
            int e = indices[idx];
            int p = atomicAdd(&cur[e], 1);
            tok[p]   = t;
            wslot[p] = weights[idx];
        }
    }
}

// ---------------- x: f32 -> bf16 once ----------------
__global__ __launch_bounds__(256) void cvt_x_kernel(const float* __restrict__ x,
                                                    unsigned short* __restrict__ xb) {
    int i = (blockIdx.x * 256 + threadIdx.x) * 8;
    float4 a = *reinterpret_cast<const float4*>(x + i);
    float4 b = *reinterpret_cast<const float4*>(x + i + 4);
    *reinterpret_cast<u16x8*>(xb + i) = pack8(a, b);
}

// ---------------- GEMM1: H = silu(X G^T) * (X U^T), 32x64 tiles, R4 dbuf pipeline ----------------
__global__ __launch_bounds__(256, 6) void gemm1_kernel(
    const unsigned short* __restrict__ xb,
    const float* __restrict__ gate, const float* __restrict__ up,
    const int* __restrict__ counts, const int* __restrict__ offsets,
    const int* __restrict__ tok, unsigned short* __restrict__ hb) {
    const int e     = blockIdx.z;
    const int n_e   = counts[e];
    const int tileM = blockIdx.y;
    if (tileM * BM >= n_e) return;
    const int off = offsets[e];
    const int n0  = blockIdx.x * BN;

    __shared__ unsigned short lA[2][ABUF];  // 2 x 2.5 KB
    __shared__ unsigned short lG[2][BBUF];  // 2 x 5 KB
    __shared__ unsigned short lU[2][BBUF];  // 2 x 5 KB  -> 25.6 KB

    const int tid  = threadIdx.x;
    const int lane = tid & 63;
    const int wn   = tid >> 6;          // wave = column quarter

    // A staging: threads 0..127 -> (row tid>>2 in 0..31, 8-elem seg tid&3)
    const int ar = tid >> 2, aseg = tid & 3;
    const int rowIdx = tileM * BM + ar;
    const int tIdx = (rowIdx < n_e) ? tok[off + rowIdx] : tok[off];
    const unsigned short* aSrc = xb + (size_t)tIdx * DDIM + aseg * 8;
    const int aOff = ar * LDT + aseg * 8;
    const bool doA = (tid < 128);
    // B staging: all 256 -> (row tid>>2 in 0..63, 8-f32 seg tid&3)
    const int br = tid >> 2, bseg = tid & 3;
    const float* gSrc = gate + ((size_t)e * IDIM + n0 + br) * DDIM + bseg * 8;
    const float* uSrc = up   + ((size_t)e * IDIM + n0 + br) * DDIM + bseg * 8;
    const int bOff = br * LDT + bseg * 8;

    f32x4 accg[2] = {};
    f32x4 accu[2] = {};

    const int fr  = lane & 15;
    const int fkb = (lane >> 4) * 8;

    uint4  av;
    float4 gv0, gv1, uv0, uv1;

    auto LOAD = [&](int k0) {
        if (doA) av = *reinterpret_cast<const uint4*>(aSrc + k0);
        gv0 = *reinterpret_cast<const float4*>(gSrc + k0);
        gv1 = *reinterpret_cast<const float4*>(gSrc + k0 + 4);
        uv0 = *reinterpret_cast<const float4*>(uSrc + k0);
        uv1 = *reinterpret_cast<const float4*>(uSrc + k0 + 4);
    };

    auto STORE = [&](int b) {
        if (doA) *reinterpret_cast<uint4*>(&lA[b][aOff]) = av;
        *reinterpret_cast<u16x8*>(&lG[b][bOff]) = pack8(gv0, gv1);
        *reinterpret_cast<u16x8*>(&lU[b][bOff]) = pack8(uv0, uv1);
    };

    auto COMPUTE = [&](int b) {
        s16x8 a0 = *reinterpret_cast<const s16x8*>(&lA[b][fr * LDT + fkb]);
        s16x8 a1 = *reinterpret_cast<const s16x8*>(&lA[b][(16 + fr) * LDT + fkb]);
        s16x8 bg = *reinterpret_cast<const s16x8*>(&lG[b][(wn * 16 + fr) * LDT + fkb]);
        s16x8 bu = *reinterpret_cast<const s16x8*>(&lU[b][(wn * 16 + fr) * LDT + fkb]);
        accg[0] = __builtin_amdgcn_mfma_f32_16x16x32_bf16(a0, bg, accg[0], 0, 0, 0);
        accg[1] = __builtin_amdgcn_mfma_f32_16x16x32_bf16(a1, bg, accg[1], 0, 0, 0);
        accu[0] = __builtin_amdgcn_mfma_f32_16x16x32_bf16(a0, bu, accu[0], 0, 0, 0);
        accu[1] = __builtin_amdgcn_mfma_f32_16x16x32_bf16(a1, bu, accu[1], 0, 0, 0);
    };

    const int NT = DDIM / BK;  // 32
    LOAD(0);
    STORE(0);
    __syncthreads();
    for (int t = 0; t < NT - 1; ++t) {
        LOAD((t + 1) * BK);    // in flight across COMPUTE (vmcnt waits at STORE)
        COMPUTE(t & 1);
        STORE((t + 1) & 1);    // opposite buffer: no pre-MFMA drain
        __syncthreads();       // single barrier per K-iter
    }
    COMPUTE((NT - 1) & 1);

    const int rbase = tileM * BM;
#pragma unroll
    for (int m = 0; m < 2; ++m)
#pragma unroll
        for (int j = 0; j < 4; ++j) {
            int rl = m * 16 + (lane >> 4) * 4 + j;
            if (rbase + rl < n_e) {
                int col = wn * 16 + fr;
                float g = accg[m][j];
                float u = accu[m][j];
                float h = (g / (1.0f + __expf(-g))) * u;
                hb[(size_t)(off + rbase + rl) * IDIM + n0 + col] = f2bf(h);
            }
        }
}

// ---------------- GEMM2: Y_rows = H D^T, weighted scatter-add, 32x64 tiles ----------------
__global__ __launch_bounds__(256, 8) void gemm2_kernel(
    const unsigned short* __restrict__ hb, const float* __restrict__ down,
    const int* __restrict__ counts, const int* __restrict__ offsets,
    const int* __restrict__ tok, const float* __restrict__ wslot,
    float* __restrict__ y) {
    const int e     = blockIdx.z;
    const int n_e   = counts[e];
    const int tileM = blockIdx.y;
    if (tileM * BM >= n_e) return;
    const int off = offsets[e];
    const int n0  = blockIdx.x * BN;

    __shared__ unsigned short lA[2][ABUF];
    __shared__ unsigned short lB[2][BBUF];  // 15.4 KB

    const int tid  = threadIdx.x;
    const int lane = tid & 63;
    const int wn   = tid >> 6;

    const int ar = tid >> 2, aseg = tid & 3;
    const int rowIdx = tileM * BM + ar;
    const int hrow = (rowIdx < n_e) ? (off + rowIdx) : off;
    const unsigned short* aSrc = hb + (size_t)hrow * IDIM + aseg * 8;
    const int aOff = ar * LDT + aseg * 8;
    const bool doA = (tid < 128);
    const int br = tid >> 2, bseg = tid & 3;
    const float* bSrc = down + ((size_t)e * DDIM + n0 + br) * IDIM + bseg * 8;
    const int bOff = br * LDT + bseg * 8;

    f32x4 acc[2] = {};

    const int fr  = lane & 15;
    const int fkb = (lane >> 4) * 8;

    uint4  av;
    float4 bv0, bv1;

    auto LOAD = [&](int k0) {
        if (doA) av = *reinterpret_cast<const uint4*>(aSrc + k0);
        bv0 = *reinterpret_cast<const float4*>(bSrc + k0);
        bv1 = *reinterpret_cast<const float4*>(bSrc + k0 + 4);
    };

    auto STORE = [&](int b) {
        if (doA) *reinterpret_cast<uint4*>(&lA[b][aOff]) = av;
        *reinterpret_cast<u16x8*>(&lB[b][bOff]) = pack8(bv0, bv1);
    };

    auto COMPUTE = [&](int b) {
        s16x8 a0 = *reinterpret_cast<const s16x8*>(&lA[b][fr * LDT + fkb]);
        s16x8 a1 = *reinterpret_cast<const s16x8*>(&lA[b][(16 + fr) * LDT + fkb]);
        s16x8 bf = *reinterpret_cast<const s16x8*>(&lB[b][(wn * 16 + fr) * LDT + fkb]);
        acc[0] = __builtin_amdgcn_mfma_f32_16x16x32_bf16(a0, bf, acc[0], 0, 0, 0);
        acc[1] = __builtin_amdgcn_mfma_f32_16x16x32_bf16(a1, bf, acc[1], 0, 0, 0);
    };

    const int NT = IDIM / BK;  // 32
    LOAD(0);
    STORE(0);
    __syncthreads();
    for (int t = 0; t < NT - 1; ++t) {
        LOAD((t + 1) * BK);
        COMPUTE(t & 1);
        STORE((t + 1) & 1);
        __syncthreads();
    }
    COMPUTE((NT - 1) & 1);

    const int rbase = tileM * BM;
#pragma unroll
    for (int m = 0; m < 2; ++m)
#pragma unroll
        for (int j = 0; j < 4; ++j) {
            int rl = m * 16 + (lane >> 4) * 4 + j;
            if (rbase + rl < n_e) {
                int col = wn * 16 + fr;
                int row = off + rbase + rl;
                float v = acc[m][j] * wslot[row];
                atomicAdd(&y[(size_t)tok[row] * DDIM + n0 + col], v);
            }
        }
}

extern "C" void kernel_launch(void* const* d_in, const int* in_sizes, int n_in,
                              void* d_out, int out_size, void* d_ws, size_t ws_size,
                              hipStream_t stream) {
    const float* x       = (const float*)d_in[0];
    const void*  mask    = d_in[1];
    const float* weights = (const float*)d_in[2];
    const int*   indices = (const int*)d_in[3];
    const float* gate    = (const float*)d_in[4];
    const float* up      = (const float*)d_in[5];
    const float* down    = (const float*)d_in[6];
    float*       y       = (float*)d_out;

    char* ws = (char*)d_ws;
    int*            counts  = (int*)ws;
    int*            offsets = (int*)(ws + 32);
    int*            tok     = (int*)(ws + 256);
    float*          wslot   = (float*)(ws + 256 + MAXROWS * 4);
    unsigned short* xb      = (unsigned short*)(ws + 65536);
    unsigned short* hb      = (unsigned short*)(ws + 65536 + (size_t)T_TOK * DDIM * 2);

    hipMemsetAsync(d_out, 0, (size_t)out_size * sizeof(float), stream);
    route_kernel<<<1, 256, 0, stream>>>(indices, weights, mask, counts, offsets, tok, wslot);
    cvt_x_kernel<<<(T_TOK * DDIM / 8) / 256, 256, 0, stream>>>(x, xb);

    // y-tiles = 32 at BM=32 -> up to 1024 rows/expert (mean 512)
    dim3 g1(IDIM / BN, 32, NEXP);
    gemm1_kernel<<<g1, 256, 0, stream>>>(xb, gate, up, counts, offsets, tok, hb);
    dim3 g2(DDIM / BN, 32, NEXP);
    gemm2_kernel<<<g2, 256, 0, stream>>>(hb, down, counts, offsets, tok, wslot, y);
}